// Round 5
// baseline (366.374 us; speedup 1.0000x reference)
//
#include <hip/hip_runtime.h>
#include <cstdint>
#include <cstddef>

typedef __bf16 bf16x8 __attribute__((ext_vector_type(8)));
typedef float f32x4 __attribute__((ext_vector_type(4)));
typedef const __attribute__((address_space(1))) void* gas_t;
typedef __attribute__((address_space(3))) void* las_t;

#define QSCALE 0.18033688011112042f   /* 0.125 * log2(e) */
#define BSCALE 0.14426950408889634f   /* 0.1 * log2(e)   */

__device__ __forceinline__ unsigned short f2bf(float f) {
  union { float f; unsigned u; } v; v.f = f;
  unsigned r = v.u + 0x7FFFu + ((v.u >> 16) & 1u);   // RNE
  return (unsigned short)(r >> 16);
}
__device__ __forceinline__ float bf2f(unsigned short h) {
  union { unsigned u; float f; } v; v.u = ((unsigned)h) << 16;
  return v.f;
}
// pack two f32 -> bf16x2 (round-half-away; inputs are finite >= 0 here)
__device__ __forceinline__ unsigned pack_bf16(float p0, float p1) {
  union { float f; unsigned u; } a, b; a.f = p0; b.f = p1;
  return __builtin_amdgcn_perm(b.u + 0x8000u, a.u + 0x8000u, 0x07060302u);
}
__device__ __forceinline__ void gll16(const void* g, void* l) {
  __builtin_amdgcn_global_load_lds((gas_t)g, (las_t)l, 16, 0, 0);
}

// ---------------- weight transpose + bf16 cast:  out[C][R] = bf16(in[R][C]) ----------------
__global__ __launch_bounds__(256) void transpose_cast(const float* __restrict__ in,
                                                      unsigned short* __restrict__ out,
                                                      int R, int C) {
  __shared__ float tile[32][33];
  int bx = blockIdx.x * 32, by = blockIdx.y * 32;
  int tx = threadIdx.x & 31, tg = threadIdx.x >> 5;
  #pragma unroll
  for (int i = 0; i < 4; i++) {
    int r = tg * 4 + i;
    tile[r][tx] = in[(size_t)(by + r) * C + bx + tx];
  }
  __syncthreads();
  #pragma unroll
  for (int i = 0; i < 4; i++) {
    int r = tg * 4 + i;
    out[(size_t)(bx + r) * R + by + tx] = f2bf(tile[tx][r]);
  }
}

struct TP4 { const float* in[4]; unsigned short* out[4]; };
__global__ __launch_bounds__(256) void transpose_cast4(TP4 p) {  // 512x512 each
  __shared__ float tile[32][33];
  const float* in = p.in[blockIdx.z];
  unsigned short* out = p.out[blockIdx.z];
  int bx = blockIdx.x * 32, by = blockIdx.y * 32;
  int tx = threadIdx.x & 31, tg = threadIdx.x >> 5;
  #pragma unroll
  for (int i = 0; i < 4; i++) {
    int r = tg * 4 + i;
    tile[r][tx] = in[(size_t)(by + r) * 512 + bx + tx];
  }
  __syncthreads();
  #pragma unroll
  for (int i = 0; i < 4; i++) {
    int r = tg * 4 + i;
    out[(size_t)(bx + r) * 512 + by + tx] = f2bf(tile[tx][r]);
  }
}

// ---------------- bias pack: bf16( adj>0 ? 0.1*edge*adj*log2e - 20 : -30000 ) ----------------
__global__ __launch_bounds__(256) void bias_pack(const int* __restrict__ adj,
                                                 const float* __restrict__ edge,
                                                 unsigned short* __restrict__ bp) {
  size_t i = ((size_t)blockIdx.x * 256 + threadIdx.x) * 4;
  int4 a = *(const int4*)(adj + i);
  float4 e = *(const float4*)(edge + i);
  ushort4 r;
  r.x = a.x > 0 ? f2bf(BSCALE * e.x * (float)a.x - 20.0f) : f2bf(-30000.0f);
  r.y = a.y > 0 ? f2bf(BSCALE * e.y * (float)a.y - 20.0f) : f2bf(-30000.0f);
  r.z = a.z > 0 ? f2bf(BSCALE * e.z * (float)a.z - 20.0f) : f2bf(-30000.0f);
  r.w = a.w > 0 ? f2bf(BSCALE * e.w * (float)a.w - 20.0f) : f2bf(-30000.0f);
  *(ushort4*)(bp + i) = r;
}

// ---------------- LayerNorm over D=512 (ln1) ----------------
__global__ __launch_bounds__(256) void ln_kernel(const float* __restrict__ x,
                                                 const float* __restrict__ g,
                                                 const float* __restrict__ bt,
                                                 unsigned short* __restrict__ out) {
  int row = blockIdx.x, tid = threadIdx.x;
  float2 v = *(const float2*)(x + (size_t)row * 512 + tid * 2);
  float s = v.x + v.y, s2 = v.x * v.x + v.y * v.y;
  #pragma unroll
  for (int m = 1; m < 64; m <<= 1) { s += __shfl_xor(s, m, 64); s2 += __shfl_xor(s2, m, 64); }
  __shared__ float red[8];
  int w = tid >> 6;
  if ((tid & 63) == 0) { red[w * 2] = s; red[w * 2 + 1] = s2; }
  __syncthreads();
  float ts = red[0] + red[2] + red[4] + red[6];
  float ts2 = red[1] + red[3] + red[5] + red[7];
  float mu = ts * (1.0f / 512.0f);
  float rs = rsqrtf(ts2 * (1.0f / 512.0f) - mu * mu + 1e-5f);
  int c = tid * 2;
  ushort2 o;
  o.x = f2bf((v.x - mu) * rs * g[c] + bt[c]);
  o.y = f2bf((v.y - mu) * rs * g[c + 1] + bt[c + 1]);
  *(ushort2*)(out + (size_t)row * 512 + c) = o;
}

// ---- fused: x1 = x + bo + p0 + p1 (bf16 partials); then LN -> n2; also store x1 fp32 ----
__global__ __launch_bounds__(256) void ln_fuse2(const float* __restrict__ x,
                                                const unsigned short* __restrict__ opp,
                                                const float* __restrict__ bo,
                                                const float* __restrict__ g,
                                                const float* __restrict__ bt,
                                                float* __restrict__ x1,
                                                unsigned short* __restrict__ n2) {
  const size_t MN = (size_t)4096 * 512;
  int row = blockIdx.x, tid = threadIdx.x;
  int c = tid * 2;
  size_t idx = (size_t)row * 512 + c;
  float2 xv = *(const float2*)(x + idx);
  ushort2 p0 = *(const ushort2*)(opp + idx);
  ushort2 p1 = *(const ushort2*)(opp + MN + idx);
  float2 v;
  v.x = xv.x + bo[c]     + bf2f(p0.x) + bf2f(p1.x);
  v.y = xv.y + bo[c + 1] + bf2f(p0.y) + bf2f(p1.y);
  float s = v.x + v.y, s2 = v.x * v.x + v.y * v.y;
  #pragma unroll
  for (int m = 1; m < 64; m <<= 1) { s += __shfl_xor(s, m, 64); s2 += __shfl_xor(s2, m, 64); }
  __shared__ float red[8];
  int w = tid >> 6;
  if ((tid & 63) == 0) { red[w * 2] = s; red[w * 2 + 1] = s2; }
  __syncthreads();
  float ts = red[0] + red[2] + red[4] + red[6];
  float ts2 = red[1] + red[3] + red[5] + red[7];
  float mu = ts * (1.0f / 512.0f);
  float rs = rsqrtf(ts2 * (1.0f / 512.0f) - mu * mu + 1e-5f);
  *(float2*)(x1 + idx) = v;
  ushort2 o;
  o.x = f2bf((v.x - mu) * rs * g[c] + bt[c]);
  o.y = f2bf((v.y - mu) * rs * g[c + 1] + bt[c + 1]);
  *(ushort2*)(n2 + idx) = o;
}

// ---------------- final: out = x1 + b2 + sum of 4 bf16 partials ----------------
__global__ __launch_bounds__(256) void final_combine(const float* __restrict__ x1,
                                                     const float* __restrict__ b2,
                                                     const unsigned short* __restrict__ mp,
                                                     float* __restrict__ out) {
  const size_t MN = (size_t)4096 * 512;
  size_t i = ((size_t)blockIdx.x * 256 + threadIdx.x) * 4;
  float4 xv = *(const float4*)(x1 + i);
  float4 bv = *(const float4*)(b2 + (i & 511));
  float4 a;
  a.x = xv.x + bv.x; a.y = xv.y + bv.y; a.z = xv.z + bv.z; a.w = xv.w + bv.w;
  #pragma unroll
  for (int sp = 0; sp < 4; sp++) {
    ushort4 p = *(const ushort4*)(mp + sp * MN + i);
    a.x += bf2f(p.x); a.y += bf2f(p.y); a.z += bf2f(p.z); a.w += bf2f(p.w);
  }
  *(float4*)(out + i) = a;
}

// ---------------- generic bf16 GEMM, BK=64, double-buffered, split-K via blockIdx.z ----------------
struct EpiQKV {
  unsigned short *q, *k, *v;
  const float *bq, *bk, *bv;
  __device__ void operator()(int m, int n, float val) const {
    int b = m >> 11, s = m & 2047;
    int which = n >> 9, col = n & 511;
    int h = col >> 6, d = col & 63;
    int bh = b * 8 + h;
    if (which == 0)      q[((size_t)bh * 2048 + s) * 64 + d] = f2bf((val + bq[col]) * QSCALE);
    else if (which == 1) k[((size_t)bh * 2048 + s) * 64 + d] = f2bf(val + bk[col]);
    else                 v[((size_t)bh * 2048 + s) * 64 + d] = f2bf(val + bv[col]);
  }
};
struct EpiPart {     // bf16 partials, one chunk per split
  unsigned short* dst; int ldn;
  __device__ void operator()(int m, int n, float val) const {
    dst[(size_t)blockIdx.z * 4096 * 512 + (size_t)m * ldn + n] = f2bf(val);
  }
};
struct EpiGelu {
  const float* b1; unsigned short* h;
  __device__ void operator()(int m, int n, float val) const {
    float t = val + b1[n];
    float gl = 0.5f * t * (1.0f + erff(t * 0.70710678118654752f));
    h[(size_t)m * 2048 + n] = f2bf(gl);
  }
};

template <typename Epi>
__global__ __launch_bounds__(256, 2) void gemm_bt(const unsigned short* __restrict__ A,
                                                  const unsigned short* __restrict__ Bt,
                                                  int lda, int ldb, int kchunk, Epi epi) {
  __shared__ unsigned short a_lds[2][128 * 64];
  __shared__ unsigned short b_lds[2][128 * 64];
  const int tid = threadIdx.x;
  const int lane = tid & 63;
  const int w = tid >> 6;
  const int l15 = lane & 15, quad = lane >> 4;
  const int wm = w >> 1, wn = w & 1;
  const int m0 = blockIdx.y * 128, n0 = blockIdx.x * 128;
  const int K0 = blockIdx.z * kchunk;
  const int nIter = kchunk >> 6;

  f32x4 acc[4][4] = {};

  #pragma unroll
  for (int i = 0; i < 4; i++) {
    int c = tid + i * 256;
    int g = c >> 6;
    int row = (g >> 1) * 16 + l15;
    int col = (g & 1) * 32 + quad * 8;
    gll16(A + (size_t)(m0 + row) * lda + K0 + col, a_lds[0] + (size_t)(c & ~63) * 8);
    gll16(Bt + (size_t)(n0 + row) * ldb + K0 + col, b_lds[0] + (size_t)(c & ~63) * 8);
  }

  for (int it = 0; it < nIter; it++) {
    const int cur = it & 1;
    __syncthreads();
    if (it + 1 < nIter) {
      const int kn = K0 + (it + 1) * 64;
      #pragma unroll
      for (int i = 0; i < 4; i++) {
        int c = tid + i * 256;
        int g = c >> 6;
        int row = (g >> 1) * 16 + l15;
        int col = (g & 1) * 32 + quad * 8;
        gll16(A + (size_t)(m0 + row) * lda + kn + col, a_lds[1 - cur] + (size_t)(c & ~63) * 8);
        gll16(Bt + (size_t)(n0 + row) * ldb + kn + col, b_lds[1 - cur] + (size_t)(c & ~63) * 8);
      }
    }
    bf16x8 af[4][2], bfr[4][2];
    #pragma unroll
    for (int t = 0; t < 4; t++)
      #pragma unroll
      for (int ks = 0; ks < 2; ks++) {
        af[t][ks]  = *(const bf16x8*)(a_lds[cur] + (((size_t)(wm * 4 + t) * 2 + ks) * 64 + lane) * 8);
        bfr[t][ks] = *(const bf16x8*)(b_lds[cur] + (((size_t)(wn * 4 + t) * 2 + ks) * 64 + lane) * 8);
      }
    #pragma unroll
    for (int mt = 0; mt < 4; mt++)
      #pragma unroll
      for (int nt = 0; nt < 4; nt++) {
        acc[mt][nt] = __builtin_amdgcn_mfma_f32_16x16x32_bf16(af[mt][0], bfr[nt][0], acc[mt][nt], 0, 0, 0);
        acc[mt][nt] = __builtin_amdgcn_mfma_f32_16x16x32_bf16(af[mt][1], bfr[nt][1], acc[mt][nt], 0, 0, 0);
      }
  }
  #pragma unroll
  for (int mt = 0; mt < 4; mt++)
    #pragma unroll
    for (int nt = 0; nt < 4; nt++)
      #pragma unroll
      for (int r = 0; r < 4; r++)
        epi(m0 + wm * 64 + mt * 16 + quad * 4 + r, n0 + wn * 64 + nt * 16 + l15, acc[mt][nt][r]);
}

// ---------------- V transpose: vb[bh][s][d] -> vbT[bh][d][s], 64x64 tiles ----------------
__global__ __launch_bounds__(256) void vt_kernel(const unsigned short* __restrict__ vb,
                                                 unsigned short* __restrict__ vbT) {
  __shared__ unsigned short tile[64][72];
  const int bh = blockIdx.y, s0 = blockIdx.x * 64;
  const int tid = threadIdx.x;
  const unsigned short* src = vb + ((size_t)bh * 2048 + s0) * 64;
  #pragma unroll
  for (int i = 0; i < 2; i++) {
    int r = (tid >> 3) + i * 32;
    int c8 = (tid & 7) * 8;
    *(uint4*)(&tile[r][c8]) = *(const uint4*)(src + (size_t)r * 64 + c8);
  }
  __syncthreads();
  unsigned short* dst = vbT + (size_t)bh * 64 * 2048 + s0;
  #pragma unroll
  for (int i = 0; i < 2; i++) {
    int d = (tid >> 3) + i * 32;
    int s8 = (tid & 7) * 8;
    ushort4 o0, o1;
    o0.x = tile[s8 + 0][d]; o0.y = tile[s8 + 1][d]; o0.z = tile[s8 + 2][d]; o0.w = tile[s8 + 3][d];
    o1.x = tile[s8 + 4][d]; o1.y = tile[s8 + 5][d]; o1.z = tile[s8 + 6][d]; o1.w = tile[s8 + 7][d];
    *(ushort4*)(dst + (size_t)d * 2048 + s8) = o0;
    *(ushort4*)(dst + (size_t)d * 2048 + s8 + 4) = o1;
  }
}

// ---------------- flash attention v5: NO LDS, NO BARRIERS ----------------
// Frags load global->VGPR directly (L1/L2 absorb the 4-wave redundancy).
// P transforms C-layout -> A-layout in-register via ds_bpermute.
// One wave = 32 q rows (2 groups of 16); block = 4 independent waves; split=4.
__global__ __launch_bounds__(256, 4) void attn_kernel(const unsigned short* __restrict__ Q,
                                                      const unsigned short* __restrict__ Kb,
                                                      const unsigned short* __restrict__ VT,
                                                      const unsigned short* __restrict__ biasp,
                                                      unsigned short* __restrict__ o_part,
                                                      float* __restrict__ l_part) {
  const int tid = threadIdx.x;
  const int lane = tid & 63, w = tid >> 6;
  const int l15 = lane & 15, quad = lane >> 4;
  const int bh = blockIdx.x, b = bh >> 3;
  const int q0 = blockIdx.y * 128 + w * 32;
  const int split = blockIdx.z;

  bf16x8 qf[2][2];
  const unsigned short* brow[2];
  #pragma unroll
  for (int g = 0; g < 2; g++) {
    const unsigned short* qrow = Q + ((size_t)bh * 2048 + q0 + g * 16 + l15) * 64;
    qf[g][0] = *(const bf16x8*)(qrow + quad * 8);
    qf[g][1] = *(const bf16x8*)(qrow + 32 + quad * 8);
    brow[g] = biasp + ((size_t)b * 2048 + q0 + g * 16 + l15) * 2048;
  }

  const unsigned short* krow = Kb + ((size_t)bh * 2048 + l15) * 64;       // + (key)*64 + dcol
  const unsigned short* vrow0 = VT + ((size_t)bh * 64 + l15) * 2048;      // + dt*16*2048 + key

  f32x4 o_acc[2][4] = {};
  float l_acc[2] = {0.0f, 0.0f};

  const int srcA = ((lane & 16) << 1) | l15;   // quad 2*(quad&1)
  const int srcB = srcA + 16;                  // quad 2*(quad&1)+1
  const bool hiTile = quad >= 2;

  const int kt0 = split * 8;
  for (int kt = kt0; kt < kt0 + 8; kt++) {
    const int kcol = kt * 64;
    #pragma unroll
    for (int H = 0; H < 2; H++) {
      // --- K frags (A-layout: m=key=l15 within tile, k=d) ---
      bf16x8 kf[2][2];
      #pragma unroll
      for (int t = 0; t < 2; t++) {
        const unsigned short* kp = krow + (size_t)(kcol + (2 * H + t) * 16) * 64;
        kf[t][0] = *(const bf16x8*)(kp + quad * 8);
        kf[t][1] = *(const bf16x8*)(kp + 32 + quad * 8);
      }
      // --- scores + exp + pack ---
      unsigned pk[2][2][2];   // [t][g][pair]
      #pragma unroll
      for (int t = 0; t < 2; t++) {
        const int mt16 = (2 * H + t) * 16;
        #pragma unroll
        for (int g = 0; g < 2; g++) {
          ushort4 bl = *(const ushort4*)(brow[g] + kcol + mt16 + quad * 4);
          f32x4 cb;
          cb[0] = bf2f(bl.x); cb[1] = bf2f(bl.y); cb[2] = bf2f(bl.z); cb[3] = bf2f(bl.w);
          f32x4 s = __builtin_amdgcn_mfma_f32_16x16x32_bf16(kf[t][0], qf[g][0], cb, 0, 0, 0);
          s = __builtin_amdgcn_mfma_f32_16x16x32_bf16(kf[t][1], qf[g][1], s, 0, 0, 0);
          float p0 = exp2f(s[0]), p1 = exp2f(s[1]), p2 = exp2f(s[2]), p3 = exp2f(s[3]);
          l_acc[g] += (p0 + p1) + (p2 + p3);
          pk[t][g][0] = pack_bf16(p0, p1);
          pk[t][g][1] = pack_bf16(p2, p3);
        }
      }
      // --- V frags (B-layout: n=d=l15 within dt tile, k=key in this H-half) ---
      bf16x8 vf[4];
      #pragma unroll
      for (int dt = 0; dt < 4; dt++)
        vf[dt] = *(const bf16x8*)(vrow0 + (size_t)dt * 16 * 2048 + kcol + H * 32 + quad * 8);
      // --- P: C-layout -> A-layout via bpermute; then PV ---
      #pragma unroll
      for (int g = 0; g < 2; g++) {
        unsigned r0a = (unsigned)__shfl((int)pk[0][g][0], srcA);
        unsigned r0b = (unsigned)__shfl((int)pk[1][g][0], srcA);
        unsigned r1a = (unsigned)__shfl((int)pk[0][g][1], srcA);
        unsigned r1b = (unsigned)__shfl((int)pk[1][g][1], srcA);
        unsigned r2a = (unsigned)__shfl((int)pk[0][g][0], srcB);
        unsigned r2b = (unsigned)__shfl((int)pk[1][g][0], srcB);
        unsigned r3a = (unsigned)__shfl((int)pk[0][g][1], srcB);
        unsigned r3b = (unsigned)__shfl((int)pk[1][g][1], srcB);
        union { uint4 u; bf16x8 v; } fr;
        fr.u.x = hiTile ? r0b : r0a;
        fr.u.y = hiTile ? r1b : r1a;
        fr.u.z = hiTile ? r2b : r2a;
        fr.u.w = hiTile ? r3b : r3a;
        #pragma unroll
        for (int dt = 0; dt < 4; dt++)
          o_acc[g][dt] = __builtin_amdgcn_mfma_f32_16x16x32_bf16(fr.v, vf[dt], o_acc[g][dt], 0, 0, 0);
      }
    }
  }

  const size_t obase = ((size_t)split * 16 + bh) * 2048;
  #pragma unroll
  for (int g = 0; g < 2; g++) {
    float l = l_acc[g];
    l += __shfl_xor(l, 16, 64);
    l += __shfl_xor(l, 32, 64);
    if (quad == 0) l_part[obase + q0 + g * 16 + l15] = l;
    #pragma unroll
    for (int dt = 0; dt < 4; dt++)
      #pragma unroll
      for (int r = 0; r < 4; r++)
        o_part[(obase + q0 + g * 16 + quad * 4 + r) * 64 + dt * 16 + l15] =
            f2bf(o_acc[g][dt][r]);
  }
}

// ---------------- combine: ao = bf16( sum_sp O_sp / sum_sp l_sp ) ----------------
__global__ __launch_bounds__(256) void combine_kernel(const unsigned short* __restrict__ o_part,
                                                      const float* __restrict__ l_part,
                                                      unsigned short* __restrict__ ao) {
  const int row = blockIdx.x;           // b*2048 + s
  const int b = row >> 11, s = row & 2047;
  const int col = threadIdx.x * 2;
  const int h = col >> 6, d = col & 63;
  const int bh = b * 8 + h;
  float ox = 0.0f, oy = 0.0f, l = 0.0f;
  #pragma unroll
  for (int sp = 0; sp < 4; sp++) {
    size_t base = (size_t)(sp * 16 + bh) * 2048 + s;
    ushort2 o = *(const ushort2*)(o_part + base * 64 + d);
    ox += bf2f(o.x); oy += bf2f(o.y);
    l += l_part[base];
  }
  float inv = 1.0f / l;
  ushort2 o;
  o.x = f2bf(ox * inv);
  o.y = f2bf(oy * inv);
  *(ushort2*)(ao + (size_t)row * 512 + col) = o;
}

// ---------------- host launch ----------------
extern "C" void kernel_launch(void* const* d_in, const int* in_sizes, int n_in,
                              void* d_out, int out_size, void* d_ws, size_t ws_size,
                              hipStream_t stream) {
  (void)in_sizes; (void)n_in; (void)out_size; (void)ws_size;
  const float* x    = (const float*)d_in[0];
  const int*   adj  = (const int*)d_in[1];
  const float* edge = (const float*)d_in[2];
  const float* ln1g = (const float*)d_in[3];
  const float* ln1b = (const float*)d_in[4];
  const float* ln2g = (const float*)d_in[5];
  const float* ln2b = (const float*)d_in[6];
  const float* wq = (const float*)d_in[7];  const float* bq = (const float*)d_in[8];
  const float* wk = (const float*)d_in[9];  const float* bk = (const float*)d_in[10];
  const float* wv = (const float*)d_in[11]; const float* bv = (const float*)d_in[12];
  const float* wo = (const float*)d_in[13]; const float* bo = (const float*)d_in[14];
  const float* w1 = (const float*)d_in[15]; const float* b1 = (const float*)d_in[16];
  const float* w2 = (const float*)d_in[17]; const float* b2 = (const float*)d_in[18];
  float* out = (float*)d_out;

  // --- workspace layout (aliased; temporally disjoint uses) -----------------
  char* ws = (char*)d_ws;
  unsigned short* qkvT = (unsigned short*)ws; ws += (size_t)1536 * 512 * 2;
  unsigned short* woT  = (unsigned short*)ws; ws += (size_t)512 * 512 * 2;
  unsigned short* w1T  = (unsigned short*)ws; ws += (size_t)2048 * 512 * 2;
  unsigned short* w2T  = (unsigned short*)ws; ws += (size_t)512 * 2048 * 2;
  // bp (bf16 2*2048*2048, dead after attn)  ||  opp (bf16 2 outproj partials)
  unsigned short* bp   = (unsigned short*)ws;
  unsigned short* opp  = (unsigned short*)ws; ws += (size_t)2 * 2048 * 2048 * 2;
  // nx (dead after QKV gemm) || n2
  unsigned short* nx   = (unsigned short*)ws;
  unsigned short* n2   = (unsigned short*)ws; ws += (size_t)4096 * 512 * 2;
  // qb (dead after attn) || ao
  unsigned short* qb   = (unsigned short*)ws;
  unsigned short* ao   = (unsigned short*)ws; ws += (size_t)4096 * 512 * 2;
  unsigned short* kb   = (unsigned short*)ws; ws += (size_t)4096 * 512 * 2;
  // vb+vbT (dead after attn) || x1 (fp32, spans both slots)
  unsigned short* vb   = (unsigned short*)ws;
  float*          x1   = (float*)ws;          ws += (size_t)4096 * 512 * 2;
  unsigned short* vbT  = (unsigned short*)ws; ws += (size_t)4096 * 512 * 2;
  // region1: [opt bf16 16.78MB | lpt 0.5MB] (dead after combine) || [hb 16.78MB | mp 16.78MB]
  char* region1 = ws;
  unsigned short* opt  = (unsigned short*)region1;
  unsigned short* hb   = (unsigned short*)region1;
  float*          lpt  = (float*)(region1 + (size_t)4 * 16 * 2048 * 64 * 2);
  unsigned short* mp   = (unsigned short*)(region1 + (size_t)4 * 16 * 2048 * 64 * 2 + 524288);

  dim3 blk(256);
  TP4 tp; tp.in[0] = wq; tp.in[1] = wk; tp.in[2] = wv; tp.in[3] = wo;
  tp.out[0] = qkvT; tp.out[1] = qkvT + (size_t)512 * 512;
  tp.out[2] = qkvT + (size_t)2 * 512 * 512; tp.out[3] = woT;
  transpose_cast4<<<dim3(16, 16, 4), blk, 0, stream>>>(tp);
  transpose_cast<<<dim3(64, 16), blk, 0, stream>>>(w1, w1T, 512, 2048);
  transpose_cast<<<dim3(16, 64), blk, 0, stream>>>(w2, w2T, 2048, 512);
  bias_pack<<<8192, blk, 0, stream>>>(adj, edge, bp);
  ln_kernel<<<4096, blk, 0, stream>>>(x, ln1g, ln1b, nx);
  gemm_bt<<<dim3(12, 32, 1), blk, 0, stream>>>(nx, qkvT, 512, 512, 512,
                                               EpiQKV{qb, kb, vb, bq, bk, bv});
  vt_kernel<<<dim3(32, 16), blk, 0, stream>>>(vb, vbT);
  attn_kernel<<<dim3(16, 16, 4), blk, 0, stream>>>(qb, kb, vbT, bp, opt, lpt);
  combine_kernel<<<4096, blk, 0, stream>>>(opt, lpt, ao);
  gemm_bt<<<dim3(4, 32, 2), blk, 0, stream>>>(ao, woT, 512, 512, 256,
                                              EpiPart{opp, 512});
  ln_fuse2<<<4096, blk, 0, stream>>>(x, opp, bo, ln2g, ln2b, x1, n2);
  gemm_bt<<<dim3(16, 32, 1), blk, 0, stream>>>(n2, w1T, 512, 512, 512,
                                               EpiGelu{b1, hb});
  gemm_bt<<<dim3(4, 32, 4), blk, 0, stream>>>(hb, w2T, 2048, 2048, 512,
                                              EpiPart{mp, 512});
  final_combine<<<2048, blk, 0, stream>>>(x1, b2, mp, out);
}

// Round 6
// 318.156 us; speedup vs baseline: 1.1516x; 1.1516x over previous
//
#include <hip/hip_runtime.h>
#include <cstdint>
#include <cstddef>

typedef __bf16 bf16x8 __attribute__((ext_vector_type(8)));
typedef float f32x4 __attribute__((ext_vector_type(4)));
typedef const __attribute__((address_space(1))) void* gas_t;
typedef __attribute__((address_space(3))) void* las_t;

#define QSCALE 0.18033688011112042f   /* 0.125 * log2(e) */
#define BSCALE 0.14426950408889634f   /* 0.1 * log2(e)   */

__device__ __forceinline__ unsigned short f2bf(float f) {
  union { float f; unsigned u; } v; v.f = f;
  unsigned r = v.u + 0x7FFFu + ((v.u >> 16) & 1u);   // RNE
  return (unsigned short)(r >> 16);
}
__device__ __forceinline__ float bf2f(unsigned short h) {
  union { unsigned u; float f; } v; v.u = ((unsigned)h) << 16;
  return v.f;
}
// pack two f32 -> bf16x2 (round-half-away; inputs are finite >= 0 here)
__device__ __forceinline__ unsigned pack_bf16(float p0, float p1) {
  union { float f; unsigned u; } a, b; a.f = p0; b.f = p1;
  return __builtin_amdgcn_perm(b.u + 0x8000u, a.u + 0x8000u, 0x07060302u);
}
__device__ __forceinline__ void gll16(const void* g, void* l) {
  __builtin_amdgcn_global_load_lds((gas_t)g, (las_t)l, 16, 0, 0);
}

// ---------------- all 6 weight transposes in ONE dispatch ----------------
struct TPAll { const float* in[6]; unsigned short* out[6]; int R[6]; int C[6]; };
__global__ __launch_bounds__(256) void transpose_all(TPAll p) {
  const int z = blockIdx.z;
  int bxb = blockIdx.x, byb = blockIdx.y;
  if (z == 5) { int t = bxb; bxb = byb; byb = t; }   // w2 is 2048 rows: swap roles
  const int R = p.R[z], C = p.C[z];
  const int bx = bxb * 32, by = byb * 32;
  if (bx >= C || by >= R) return;
  const float* in = p.in[z];
  unsigned short* out = p.out[z];
  __shared__ float tile[32][33];
  int tx = threadIdx.x & 31, tg = threadIdx.x >> 5;
  #pragma unroll
  for (int i = 0; i < 4; i++) {
    int r = tg * 4 + i;
    tile[r][tx] = in[(size_t)(by + r) * C + bx + tx];
  }
  __syncthreads();
  #pragma unroll
  for (int i = 0; i < 4; i++) {
    int r = tg * 4 + i;
    out[(size_t)(bx + r) * R + by + tx] = f2bf(tile[tx][r]);
  }
}

// ---------------- bias pack: bf16( adj>0 ? 0.1*edge*adj*log2e - 20 : -30000 ) ----------------
__global__ __launch_bounds__(256) void bias_pack(const int* __restrict__ adj,
                                                 const float* __restrict__ edge,
                                                 unsigned short* __restrict__ bp) {
  size_t i = ((size_t)blockIdx.x * 256 + threadIdx.x) * 4;
  int4 a = *(const int4*)(adj + i);
  float4 e = *(const float4*)(edge + i);
  ushort4 r;
  r.x = a.x > 0 ? f2bf(BSCALE * e.x * (float)a.x - 20.0f) : f2bf(-30000.0f);
  r.y = a.y > 0 ? f2bf(BSCALE * e.y * (float)a.y - 20.0f) : f2bf(-30000.0f);
  r.z = a.z > 0 ? f2bf(BSCALE * e.z * (float)a.z - 20.0f) : f2bf(-30000.0f);
  r.w = a.w > 0 ? f2bf(BSCALE * e.w * (float)a.w - 20.0f) : f2bf(-30000.0f);
  *(ushort4*)(bp + i) = r;
}

// ---------------- LayerNorm over D=512 (ln1) ----------------
__global__ __launch_bounds__(256) void ln_kernel(const float* __restrict__ x,
                                                 const float* __restrict__ g,
                                                 const float* __restrict__ bt,
                                                 unsigned short* __restrict__ out) {
  int row = blockIdx.x, tid = threadIdx.x;
  float2 v = *(const float2*)(x + (size_t)row * 512 + tid * 2);
  float s = v.x + v.y, s2 = v.x * v.x + v.y * v.y;
  #pragma unroll
  for (int m = 1; m < 64; m <<= 1) { s += __shfl_xor(s, m, 64); s2 += __shfl_xor(s2, m, 64); }
  __shared__ float red[8];
  int w = tid >> 6;
  if ((tid & 63) == 0) { red[w * 2] = s; red[w * 2 + 1] = s2; }
  __syncthreads();
  float ts = red[0] + red[2] + red[4] + red[6];
  float ts2 = red[1] + red[3] + red[5] + red[7];
  float mu = ts * (1.0f / 512.0f);
  float rs = rsqrtf(ts2 * (1.0f / 512.0f) - mu * mu + 1e-5f);
  int c = tid * 2;
  ushort2 o;
  o.x = f2bf((v.x - mu) * rs * g[c] + bt[c]);
  o.y = f2bf((v.y - mu) * rs * g[c + 1] + bt[c + 1]);
  *(ushort2*)(out + (size_t)row * 512 + c) = o;
}

// ---- fused: x1 = x + bo + p0 + p1 (bf16 partials); then LN -> n2; also store x1 fp32 ----
__global__ __launch_bounds__(256) void ln_fuse2(const float* __restrict__ x,
                                                const unsigned short* __restrict__ opp,
                                                const float* __restrict__ bo,
                                                const float* __restrict__ g,
                                                const float* __restrict__ bt,
                                                float* __restrict__ x1,
                                                unsigned short* __restrict__ n2) {
  const size_t MN = (size_t)4096 * 512;
  int row = blockIdx.x, tid = threadIdx.x;
  int c = tid * 2;
  size_t idx = (size_t)row * 512 + c;
  float2 xv = *(const float2*)(x + idx);
  ushort2 p0 = *(const ushort2*)(opp + idx);
  ushort2 p1 = *(const ushort2*)(opp + MN + idx);
  float2 v;
  v.x = xv.x + bo[c]     + bf2f(p0.x) + bf2f(p1.x);
  v.y = xv.y + bo[c + 1] + bf2f(p0.y) + bf2f(p1.y);
  float s = v.x + v.y, s2 = v.x * v.x + v.y * v.y;
  #pragma unroll
  for (int m = 1; m < 64; m <<= 1) { s += __shfl_xor(s, m, 64); s2 += __shfl_xor(s2, m, 64); }
  __shared__ float red[8];
  int w = tid >> 6;
  if ((tid & 63) == 0) { red[w * 2] = s; red[w * 2 + 1] = s2; }
  __syncthreads();
  float ts = red[0] + red[2] + red[4] + red[6];
  float ts2 = red[1] + red[3] + red[5] + red[7];
  float mu = ts * (1.0f / 512.0f);
  float rs = rsqrtf(ts2 * (1.0f / 512.0f) - mu * mu + 1e-5f);
  *(float2*)(x1 + idx) = v;
  ushort2 o;
  o.x = f2bf((v.x - mu) * rs * g[c] + bt[c]);
  o.y = f2bf((v.y - mu) * rs * g[c + 1] + bt[c + 1]);
  *(ushort2*)(n2 + idx) = o;
}

// ---------------- final: out = x1 + b2 + sum of 4 bf16 partials ----------------
__global__ __launch_bounds__(256) void final_combine(const float* __restrict__ x1,
                                                     const float* __restrict__ b2,
                                                     const unsigned short* __restrict__ mp,
                                                     float* __restrict__ out) {
  const size_t MN = (size_t)4096 * 512;
  size_t i = ((size_t)blockIdx.x * 256 + threadIdx.x) * 4;
  float4 xv = *(const float4*)(x1 + i);
  float4 bv = *(const float4*)(b2 + (i & 511));
  float4 a;
  a.x = xv.x + bv.x; a.y = xv.y + bv.y; a.z = xv.z + bv.z; a.w = xv.w + bv.w;
  #pragma unroll
  for (int sp = 0; sp < 4; sp++) {
    ushort4 p = *(const ushort4*)(mp + sp * MN + i);
    a.x += bf2f(p.x); a.y += bf2f(p.y); a.z += bf2f(p.z); a.w += bf2f(p.w);
  }
  *(float4*)(out + i) = a;
}

// ---------------- generic bf16 GEMM, BK=64, single-buffered, 3 blocks/CU ----------------
struct EpiQKV {
  unsigned short *q, *k, *v;
  const float *bq, *bk, *bv;
  __device__ void operator()(int m, int n, float val) const {
    int b = m >> 11, s = m & 2047;
    int which = n >> 9, col = n & 511;
    int h = col >> 6, d = col & 63;
    int bh = b * 8 + h;
    if (which == 0)      q[((size_t)bh * 2048 + s) * 64 + d] = f2bf((val + bq[col]) * QSCALE);
    else if (which == 1) k[((size_t)bh * 2048 + s) * 64 + d] = f2bf(val + bk[col]);
    else                 v[((size_t)bh * 2048 + s) * 64 + d] = f2bf(val + bv[col]);
  }
};
struct EpiPart {     // bf16 partials, one chunk per split
  unsigned short* dst; int ldn;
  __device__ void operator()(int m, int n, float val) const {
    dst[(size_t)blockIdx.z * 4096 * 512 + (size_t)m * ldn + n] = f2bf(val);
  }
};
struct EpiGelu {
  const float* b1; unsigned short* h;
  __device__ void operator()(int m, int n, float val) const {
    float t = val + b1[n];
    float gl = 0.5f * t * (1.0f + erff(t * 0.70710678118654752f));
    h[(size_t)m * 2048 + n] = f2bf(gl);
  }
};

template <typename Epi>
__global__ __launch_bounds__(256, 3) void gemm_bt(const unsigned short* __restrict__ A,
                                                  const unsigned short* __restrict__ Bt,
                                                  int lda, int ldb, int kchunk, Epi epi) {
  __shared__ unsigned short a_lds[128 * 64];
  __shared__ unsigned short b_lds[128 * 64];
  const int tid = threadIdx.x;
  const int lane = tid & 63;
  const int w = tid >> 6;
  const int l15 = lane & 15, quad = lane >> 4;
  const int wm = w >> 1, wn = w & 1;
  const int m0 = blockIdx.y * 128, n0 = blockIdx.x * 128;
  const int K0 = blockIdx.z * kchunk, K1 = K0 + kchunk;

  f32x4 acc[4][4] = {};

  for (int k0 = K0; k0 < K1; k0 += 64) {
    __syncthreads();
    #pragma unroll
    for (int i = 0; i < 4; i++) {
      int c = tid + i * 256;
      int g = c >> 6;                      // 0..15
      int row = (g >> 1) * 16 + l15;
      int col = (g & 1) * 32 + quad * 8;
      gll16(A + (size_t)(m0 + row) * lda + k0 + col, a_lds + (size_t)(c & ~63) * 8);
      gll16(Bt + (size_t)(n0 + row) * ldb + k0 + col, b_lds + (size_t)(c & ~63) * 8);
    }
    __syncthreads();
    bf16x8 af[4][2], bfr[4][2];
    #pragma unroll
    for (int t = 0; t < 4; t++)
      #pragma unroll
      for (int ks = 0; ks < 2; ks++) {
        af[t][ks]  = *(const bf16x8*)(a_lds + (((size_t)(wm * 4 + t) * 2 + ks) * 64 + lane) * 8);
        bfr[t][ks] = *(const bf16x8*)(b_lds + (((size_t)(wn * 4 + t) * 2 + ks) * 64 + lane) * 8);
      }
    #pragma unroll
    for (int mt = 0; mt < 4; mt++)
      #pragma unroll
      for (int nt = 0; nt < 4; nt++) {
        acc[mt][nt] = __builtin_amdgcn_mfma_f32_16x16x32_bf16(af[mt][0], bfr[nt][0], acc[mt][nt], 0, 0, 0);
        acc[mt][nt] = __builtin_amdgcn_mfma_f32_16x16x32_bf16(af[mt][1], bfr[nt][1], acc[mt][nt], 0, 0, 0);
      }
  }
  #pragma unroll
  for (int mt = 0; mt < 4; mt++)
    #pragma unroll
    for (int nt = 0; nt < 4; nt++)
      #pragma unroll
      for (int r = 0; r < 4; r++)
        epi(m0 + wm * 64 + mt * 16 + quad * 4 + r, n0 + wn * 64 + nt * 16 + l15, acc[mt][nt][r]);
}

// ---------------- V transpose: vb[bh][s][d] -> vbT[bh][d][s], 64x64 tiles ----------------
__global__ __launch_bounds__(256) void vt_kernel(const unsigned short* __restrict__ vb,
                                                 unsigned short* __restrict__ vbT) {
  __shared__ unsigned short tile[64][72];
  const int bh = blockIdx.y, s0 = blockIdx.x * 64;
  const int tid = threadIdx.x;
  const unsigned short* src = vb + ((size_t)bh * 2048 + s0) * 64;
  #pragma unroll
  for (int i = 0; i < 2; i++) {
    int r = (tid >> 3) + i * 32;
    int c8 = (tid & 7) * 8;
    *(uint4*)(&tile[r][c8]) = *(const uint4*)(src + (size_t)r * 64 + c8);
  }
  __syncthreads();
  unsigned short* dst = vbT + (size_t)bh * 64 * 2048 + s0;
  #pragma unroll
  for (int i = 0; i < 2; i++) {
    int d = (tid >> 3) + i * 32;
    int s8 = (tid & 7) * 8;
    ushort4 o0, o1;
    o0.x = tile[s8 + 0][d]; o0.y = tile[s8 + 1][d]; o0.z = tile[s8 + 2][d]; o0.w = tile[s8 + 3][d];
    o1.x = tile[s8 + 4][d]; o1.y = tile[s8 + 5][d]; o1.z = tile[s8 + 6][d]; o1.w = tile[s8 + 7][d];
    *(ushort4*)(dst + (size_t)d * 2048 + s8) = o0;
    *(ushort4*)(dst + (size_t)d * 2048 + s8 + 4) = o1;
  }
}

// ---------------- flash attention v6: dbuf LDS staging + in-register P transpose ----------------
// 32KB LDS, 4 blocks/CU; one barrier per 64-key tile; no P LDS round-trip.
__global__ __launch_bounds__(256, 4) void attn_kernel(const unsigned short* __restrict__ Q,
                                                      const unsigned short* __restrict__ Kb,
                                                      const unsigned short* __restrict__ VT,
                                                      const unsigned short* __restrict__ biasp,
                                                      unsigned short* __restrict__ o_part,
                                                      float* __restrict__ l_part) {
  __shared__ unsigned short k_lds[2][64 * 64];
  __shared__ unsigned short v_lds[2][64 * 64];

  const int tid = threadIdx.x;
  const int lane = tid & 63, w = tid >> 6;
  const int l15 = lane & 15, quad = lane >> 4;
  const int bh = blockIdx.x, b = bh >> 3;
  const int q0 = blockIdx.y * 128 + w * 32;
  const int split = blockIdx.z;

  bf16x8 qf[2][2];
  const unsigned short* brow[2];
  #pragma unroll
  for (int g = 0; g < 2; g++) {
    const unsigned short* qrow = Q + ((size_t)bh * 2048 + q0 + g * 16 + l15) * 64;
    qf[g][0] = *(const bf16x8*)(qrow + quad * 8);
    qf[g][1] = *(const bf16x8*)(qrow + 32 + quad * 8);
    brow[g] = biasp + ((size_t)b * 2048 + q0 + g * 16 + l15) * 2048;
  }

  f32x4 o_acc[2][4] = {};
  float l_acc[2] = {0.0f, 0.0f};

  const unsigned short* kbase = Kb + (size_t)bh * 2048 * 64;
  const unsigned short* vbase = VT + (size_t)bh * 64 * 2048;

  // in-register P transpose lane plumbing (verified round 5)
  const int srcA = ((lane & 16) << 1) | l15;
  const int srcB = srcA + 16;
  const bool hiTile = quad >= 2;

  const int kt0 = split * 8, kt1 = kt0 + 8;

  // prologue: stage kt0 into buffer 0; prefetch its bias
  #pragma unroll
  for (int i = 0; i < 2; i++) {
    int c = tid + i * 256;
    int g = c >> 6;
    int rr = (g >> 1) * 16 + l15;
    int cc = (g & 1) * 32 + quad * 8;
    gll16(kbase + (size_t)(kt0 * 64 + rr) * 64 + cc, k_lds[0] + (size_t)(c & ~63) * 8);
    gll16(vbase + (size_t)rr * 2048 + kt0 * 64 + cc, v_lds[0] + (size_t)(c & ~63) * 8);
  }
  ushort4 blc[2][4];
  #pragma unroll
  for (int g = 0; g < 2; g++)
    #pragma unroll
    for (int mt = 0; mt < 4; mt++)
      blc[g][mt] = *(const ushort4*)(brow[g] + kt0 * 64 + mt * 16 + quad * 4);

  for (int kt = kt0; kt < kt1; kt++) {
    const int cur = (kt - kt0) & 1;
    const int kcol = kt * 64;
    __syncthreads();          // buf[cur] staged (vmcnt drained); buf[1-cur] free

    if (kt + 1 < kt1) {
      const int kcn = (kt + 1) * 64;
      #pragma unroll
      for (int i = 0; i < 2; i++) {
        int c = tid + i * 256;
        int g = c >> 6;
        int rr = (g >> 1) * 16 + l15;
        int cc = (g & 1) * 32 + quad * 8;
        gll16(kbase + (size_t)(kcn + rr) * 64 + cc, k_lds[1 - cur] + (size_t)(c & ~63) * 8);
        gll16(vbase + (size_t)rr * 2048 + kcn + cc, v_lds[1 - cur] + (size_t)(c & ~63) * 8);
      }
    }
    const int ktn64 = (kt + 1 < kt1) ? (kt + 1) * 64 : kcol;
    ushort4 bln[2][4];
    #pragma unroll
    for (int g = 0; g < 2; g++)
      #pragma unroll
      for (int mt = 0; mt < 4; mt++)
        bln[g][mt] = *(const ushort4*)(brow[g] + ktn64 + mt * 16 + quad * 4);

    #pragma unroll
    for (int H = 0; H < 2; H++) {
      // K frags from LDS (A-layout)
      bf16x8 kf[2][2];
      #pragma unroll
      for (int t = 0; t < 2; t++) {
        const int mtile = 2 * H + t;
        kf[t][0] = *(const bf16x8*)(k_lds[cur] + ((size_t)(mtile * 2 + 0) * 64 + lane) * 8);
        kf[t][1] = *(const bf16x8*)(k_lds[cur] + ((size_t)(mtile * 2 + 1) * 64 + lane) * 8);
      }
      // scores + exp + pack
      unsigned pk[2][2][2];   // [t][g][pair]
      #pragma unroll
      for (int t = 0; t < 2; t++) {
        #pragma unroll
        for (int g = 0; g < 2; g++) {
          ushort4 bl = blc[g][2 * H + t];
          f32x4 cb;
          cb[0] = bf2f(bl.x); cb[1] = bf2f(bl.y); cb[2] = bf2f(bl.z); cb[3] = bf2f(bl.w);
          f32x4 s = __builtin_amdgcn_mfma_f32_16x16x32_bf16(kf[t][0], qf[g][0], cb, 0, 0, 0);
          s = __builtin_amdgcn_mfma_f32_16x16x32_bf16(kf[t][1], qf[g][1], s, 0, 0, 0);
          float p0 = exp2f(s[0]), p1 = exp2f(s[1]), p2 = exp2f(s[2]), p3 = exp2f(s[3]);
          l_acc[g] += (p0 + p1) + (p2 + p3);
          pk[t][g][0] = pack_bf16(p0, p1);
          pk[t][g][1] = pack_bf16(p2, p3);
        }
      }
      // V frags from LDS (B-layout, this H-half of keys)
      bf16x8 vf[4];
      #pragma unroll
      for (int dt = 0; dt < 4; dt++)
        vf[dt] = *(const bf16x8*)(v_lds[cur] + ((size_t)(dt * 2 + H) * 64 + lane) * 8);
      // P: C-layout -> A-layout via cross-lane permute; then PV
      #pragma unroll
      for (int g = 0; g < 2; g++) {
        unsigned r0a = (unsigned)__shfl((int)pk[0][g][0], srcA);
        unsigned r0b = (unsigned)__shfl((int)pk[1][g][0], srcA);
        unsigned r1a = (unsigned)__shfl((int)pk[0][g][1], srcA);
        unsigned r1b = (unsigned)__shfl((int)pk[1][g][1], srcA);
        unsigned r2a = (unsigned)__shfl((int)pk[0][g][0], srcB);
        unsigned r2b = (unsigned)__shfl((int)pk[1][g][0], srcB);
        unsigned r3a = (unsigned)__shfl((int)pk[0][g][1], srcB);
        unsigned r3b = (unsigned)__shfl((int)pk[1][g][1], srcB);
        union { uint4 u; bf16x8 v; } fr;
        fr.u.x = hiTile ? r0b : r0a;
        fr.u.y = hiTile ? r1b : r1a;
        fr.u.z = hiTile ? r2b : r2a;
        fr.u.w = hiTile ? r3b : r3a;
        #pragma unroll
        for (int dt = 0; dt < 4; dt++)
          o_acc[g][dt] = __builtin_amdgcn_mfma_f32_16x16x32_bf16(fr.v, vf[dt], o_acc[g][dt], 0, 0, 0);
      }
    }

    #pragma unroll
    for (int g = 0; g < 2; g++)
      #pragma unroll
      for (int mt = 0; mt < 4; mt++)
        blc[g][mt] = bln[g][mt];
  }

  const size_t obase = ((size_t)split * 16 + bh) * 2048;
  #pragma unroll
  for (int g = 0; g < 2; g++) {
    float l = l_acc[g];
    l += __shfl_xor(l, 16, 64);
    l += __shfl_xor(l, 32, 64);
    if (quad == 0) l_part[obase + q0 + g * 16 + l15] = l;
    #pragma unroll
    for (int dt = 0; dt < 4; dt++)
      #pragma unroll
      for (int r = 0; r < 4; r++)
        o_part[(obase + q0 + g * 16 + quad * 4 + r) * 64 + dt * 16 + l15] =
            f2bf(o_acc[g][dt][r]);
  }
}

// ---------------- combine: ao = bf16( sum_sp O_sp / sum_sp l_sp ) ----------------
__global__ __launch_bounds__(256) void combine_kernel(const unsigned short* __restrict__ o_part,
                                                      const float* __restrict__ l_part,
                                                      unsigned short* __restrict__ ao) {
  const int row = blockIdx.x;           // b*2048 + s
  const int b = row >> 11, s = row & 2047;
  const int col = threadIdx.x * 2;
  const int h = col >> 6, d = col & 63;
  const int bh = b * 8 + h;
  float ox = 0.0f, oy = 0.0f, l = 0.0f;
  #pragma unroll
  for (int sp = 0; sp < 4; sp++) {
    size_t base = (size_t)(sp * 16 + bh) * 2048 + s;
    ushort2 o = *(const ushort2*)(o_part + base * 64 + d);
    ox += bf2f(o.x); oy += bf2f(o.y);
    l += l_part[base];
  }
  float inv = 1.0f / l;
  ushort2 o;
  o.x = f2bf(ox * inv);
  o.y = f2bf(oy * inv);
  *(ushort2*)(ao + (size_t)row * 512 + col) = o;
}

// ---------------- host launch ----------------
extern "C" void kernel_launch(void* const* d_in, const int* in_sizes, int n_in,
                              void* d_out, int out_size, void* d_ws, size_t ws_size,
                              hipStream_t stream) {
  (void)in_sizes; (void)n_in; (void)out_size; (void)ws_size;
  const float* x    = (const float*)d_in[0];
  const int*   adj  = (const int*)d_in[1];
  const float* edge = (const float*)d_in[2];
  const float* ln1g = (const float*)d_in[3];
  const float* ln1b = (const float*)d_in[4];
  const float* ln2g = (const float*)d_in[5];
  const float* ln2b = (const float*)d_in[6];
  const float* wq = (const float*)d_in[7];  const float* bq = (const float*)d_in[8];
  const float* wk = (const float*)d_in[9];  const float* bk = (const float*)d_in[10];
  const float* wv = (const float*)d_in[11]; const float* bv = (const float*)d_in[12];
  const float* wo = (const float*)d_in[13]; const float* bo = (const float*)d_in[14];
  const float* w1 = (const float*)d_in[15]; const float* b1 = (const float*)d_in[16];
  const float* w2 = (const float*)d_in[17]; const float* b2 = (const float*)d_in[18];
  float* out = (float*)d_out;

  // --- workspace layout (aliased; temporally disjoint uses) -----------------
  char* ws = (char*)d_ws;
  unsigned short* qkvT = (unsigned short*)ws; ws += (size_t)1536 * 512 * 2;
  unsigned short* woT  = (unsigned short*)ws; ws += (size_t)512 * 512 * 2;
  unsigned short* w1T  = (unsigned short*)ws; ws += (size_t)2048 * 512 * 2;
  unsigned short* w2T  = (unsigned short*)ws; ws += (size_t)512 * 2048 * 2;
  // bp (bf16 2*2048*2048, dead after attn)  ||  opp (bf16 2 outproj partials)
  unsigned short* bp   = (unsigned short*)ws;
  unsigned short* opp  = (unsigned short*)ws; ws += (size_t)2 * 2048 * 2048 * 2;
  // nx (dead after QKV gemm) || n2
  unsigned short* nx   = (unsigned short*)ws;
  unsigned short* n2   = (unsigned short*)ws; ws += (size_t)4096 * 512 * 2;
  // qb (dead after attn) || ao
  unsigned short* qb   = (unsigned short*)ws;
  unsigned short* ao   = (unsigned short*)ws; ws += (size_t)4096 * 512 * 2;
  unsigned short* kb   = (unsigned short*)ws; ws += (size_t)4096 * 512 * 2;
  // vb+vbT (dead after attn) || x1 (fp32, spans both slots)
  unsigned short* vb   = (unsigned short*)ws;
  float*          x1   = (float*)ws;          ws += (size_t)4096 * 512 * 2;
  unsigned short* vbT  = (unsigned short*)ws; ws += (size_t)4096 * 512 * 2;
  // region1: [opt bf16 16.78MB | lpt 0.5MB] (dead after combine) || [hb 16.78MB | mp 16.78MB]
  char* region1 = ws;
  unsigned short* opt  = (unsigned short*)region1;
  unsigned short* hb   = (unsigned short*)region1;
  float*          lpt  = (float*)(region1 + (size_t)4 * 16 * 2048 * 64 * 2);
  unsigned short* mp   = (unsigned short*)(region1 + (size_t)4 * 16 * 2048 * 64 * 2 + 524288);

  dim3 blk(256);
  TPAll tp;
  tp.in[0] = wq; tp.in[1] = wk; tp.in[2] = wv; tp.in[3] = wo; tp.in[4] = w1; tp.in[5] = w2;
  tp.out[0] = qkvT; tp.out[1] = qkvT + (size_t)512 * 512;
  tp.out[2] = qkvT + (size_t)2 * 512 * 512; tp.out[3] = woT; tp.out[4] = w1T; tp.out[5] = w2T;
  tp.R[0] = tp.R[1] = tp.R[2] = tp.R[3] = 512; tp.R[4] = 512; tp.R[5] = 2048;
  tp.C[0] = tp.C[1] = tp.C[2] = tp.C[3] = 512; tp.C[4] = 2048; tp.C[5] = 512;
  transpose_all<<<dim3(64, 16, 6), blk, 0, stream>>>(tp);
  bias_pack<<<8192, blk, 0, stream>>>(adj, edge, bp);
  ln_kernel<<<4096, blk, 0, stream>>>(x, ln1g, ln1b, nx);
  gemm_bt<<<dim3(12, 32, 1), blk, 0, stream>>>(nx, qkvT, 512, 512, 512,
                                               EpiQKV{qb, kb, vb, bq, bk, bv});
  vt_kernel<<<dim3(32, 16), blk, 0, stream>>>(vb, vbT);
  attn_kernel<<<dim3(16, 16, 4), blk, 0, stream>>>(qb, kb, vbT, bp, opt, lpt);
  combine_kernel<<<4096, blk, 0, stream>>>(opt, lpt, ao);
  gemm_bt<<<dim3(4, 32, 2), blk, 0, stream>>>(ao, woT, 512, 512, 256,
                                              EpiPart{opp, 512});
  ln_fuse2<<<4096, blk, 0, stream>>>(x, opp, bo, ln2g, ln2b, x1, n2);
  gemm_bt<<<dim3(16, 32, 1), blk, 0, stream>>>(n2, w1T, 512, 512, 512,
                                               EpiGelu{b1, hb});
  gemm_bt<<<dim3(4, 32, 4), blk, 0, stream>>>(hb, w2T, 2048, 2048, 512,
                                              EpiPart{mp, 512});
  final_combine<<<2048, blk, 0, stream>>>(x1, b2, mp, out);
}